// Round 1
// 341.679 us; speedup vs baseline: 1.0006x; 1.0006x over previous
//
#include <hip/hip_runtime.h>
#include <math.h>

// B=8, C=256, H=W=64, G=4, K=3, KK=9, Cg=64
// Round 10: k_offconv restructured from per-tap staging (9x stage/sync/mfma/sync,
// 18 barriers/block, 14 MFMA per phase) to single-stage: the 3x66 input window
// shared by all 9 taps is staged to LDS once, one barrier, then 126 MFMAs/wave
// run as one barrier-free burst. Staged global bytes drop 3x (rows reused across
// ky). All other kernels identical to round 9 (342 us baseline).
// ws layout (bytes):
//   wpart bf16 [4][8][108][4096] @ 0          (28,311,552)
//   wo_a  bf16 [112][2304]       @ 28,311,552 (516,096)   k = tap*256+ch
//   wd_a  bf16 [4][64][576]      @ 28,827,648 (294,912)   k = tap*64+cl
//   x2    bf16 [256][4356][8]    @ 29,122,560 (17,842,176)
// total 46,964,736 B (< proven 48.3 MB)

typedef __attribute__((ext_vector_type(4))) short s16x4;
typedef __attribute__((ext_vector_type(8))) short s16x8;
typedef __attribute__((ext_vector_type(4))) float f32x4;

union S8 { s16x8 v; s16x4 h[2]; };

__device__ __forceinline__ s16x8 ld8(const short* p) {
  S8 r;
  r.h[0] = *(const s16x4*)p;
  r.h[1] = *(const s16x4*)(p + 4);
  return r.v;
}

__device__ __forceinline__ unsigned short bfr(float v) {  // RNE to bf16
  unsigned u = __float_as_uint(v);
  u = (u + 0x7FFFu + ((u >> 16) & 1u)) >> 16;
  return (unsigned short)u;
}
__device__ __forceinline__ float bff(unsigned short s) {
  return __uint_as_float(((unsigned)s) << 16);
}
__device__ __forceinline__ float bf(short s) {
  return __uint_as_float(((unsigned)(unsigned short)s) << 16);
}

__global__ __launch_bounds__(256) void k_prep(
    const float* __restrict__ w_off, const float* __restrict__ w_dcn,
    short* __restrict__ wo_a, short* __restrict__ wd_a) {
  int i = blockIdx.x * 256 + threadIdx.x;
  const int n1 = 112 * 2304;
  if (i < n1) {
    int co = i / 2304, k = i % 2304;
    int tap = k >> 8, ch = k & 255;  // k = tap*256 + ch
    float v = (co < 108) ? w_off[(co * 256 + ch) * 9 + tap] : 0.f;
    wo_a[i] = (short)bfr(v);
  } else {
    int j = i - n1;  // exactly 147456 remaining threads (grid 1584*256)
    int g = j / 36864, r = j % 36864;
    int co = r / 576, k = r % 576;
    int kk = k >> 6, cl = k & 63;  // k = tap*64 + cl
    wd_a[j] = (short)bfr(w_dcn[((g * 64 + co) * 64 + cl) * 9 + kk]);
  }
}

// x -> chunked bf16 NHWC with zero halo.
// interior: thread = (b, c2, pixel); border: zero 16B slots.
__global__ __launch_bounds__(256) void k_x2(
    const float* __restrict__ x, short* __restrict__ x2) {
  int id = blockIdx.x * 256 + threadIdx.x;
  const int n1 = 8 * 32 * 4096;  // 1,048,576 interior items
  if (id < n1) {
    int pc = id & 4095;
    int c2 = (id >> 12) & 31;
    int b = id >> 17;
    int h = pc >> 6, w = pc & 63;
    const float* xp = x + ((size_t)(b * 256 + c2 * 8)) * 4096 + pc;
    short* o = x2 + ((size_t)(b * 32 + c2) * 4356 + (h + 1) * 66 + (w + 1)) * 8;
    s16x4 v0, v1;
#pragma unroll
    for (int i = 0; i < 4; ++i) {
      v0[i] = (short)bfr(xp[(size_t)i * 4096]);
      v1[i] = (short)bfr(xp[(size_t)(i + 4) * 4096]);
    }
    *(s16x4*)o = v0;
    *(s16x4*)(o + 4) = v1;
  } else {
    int j = id - n1;  // grid sized exactly: j < 256*260
    int plane = j / 260, r = j % 260;
    int h, w;
    if (r < 66) { h = 0; w = r; }
    else if (r < 132) { h = 65; w = r - 66; }
    else if (r < 196) { h = r - 131; w = 0; }
    else { h = r - 195; w = 65; }
    short* o = x2 + ((size_t)plane * 4356 + h * 66 + w) * 8;
    s16x4 z = {0, 0, 0, 0};
    *(s16x4*)o = z;
    *(s16x4*)(o + 4) = z;
  }
}

// Offset conv, bf16 MFMA, K-split by channel-quarter, XCD-pinned slices.
// Round 10: single-stage structure. The 3-row x 66-col padded input window
// (64 ch bf16, 26.9 KB) shared by all 9 taps is staged once; one barrier;
// then all 9 taps x 2 k-halves x 7 m-tiles = 126 MFMAs/wave run with no
// intervening barrier (weight loads are L2-resident, compiler can pipeline).
__global__ __launch_bounds__(256) void k_offconv(
    const short* __restrict__ x2, const short* __restrict__ wo_a,
    const float* __restrict__ b_off, short* __restrict__ wpart) {
  __shared__ short p_s[3 * 66 * 68];  // [row 0..2][pix 0..65][64 ch + 4 pad]
  int bi = blockIdx.x;  // 2048
  int xcd = bi & 7;
  int j = bi >> 3;
  int slice = xcd * 4 + (j & 3);  // 0..31, pinned to xcd
  int h = j >> 2;                 // 0..63
  int part = slice >> 3, b = slice & 7;
  int tid = threadIdx.x;
  int lane = tid & 63, wv = tid >> 6;
  int quad = lane >> 4, l15 = lane & 15;

  f32x4 zero4 = {0.f, 0.f, 0.f, 0.f};
  f32x4 acc[7];
#pragma unroll
  for (int i = 0; i < 7; ++i) acc[i] = zero4;

  // planes for this block's 64 channels: (b*32 + part*8 + ck), ck = 0..7
  const short* x2b = x2 + (size_t)(b * 32 + part * 8) * 34848;

  // Stage the full 3x66 window once: 1584 x 16B chunks.
  // it = ck*198 + rp  (rp = row*66 + pix): consecutive lanes -> consecutive
  // pixels within one plane -> ~1KB contiguous per wave per plane.
  for (int it = tid; it < 1584; it += 256) {
    int ck = it / 198;
    int rp = it - ck * 198;
    const short* src = x2b + (size_t)ck * 34848 + ((size_t)h * 66 + rp) * 8;
    S8 v;
    v.v = *(const s16x8*)src;  // 16B aligned
    short* dst = &p_s[rp * 68 + ck * 8];
    *(s16x4*)dst = v.h[0];
    *(s16x4*)(dst + 4) = v.h[1];
  }
  __syncthreads();

  int nb = 16 * wv + l15;  // output column this lane owns (B-fragment row)
#pragma unroll
  for (int tap = 0; tap < 9; ++tap) {
    int ky = tap / 3, kx = tap % 3;
    // output col nb, tap (ky,kx) samples padded (h+ky, nb+kx) = staged row ky
    const short* bp = &p_s[(ky * 66 + nb + kx) * 68];
#pragma unroll
    for (int s = 0; s < 2; ++s) {
      int k0 = 32 * s + quad * 8;
      s16x8 bf_f = ld8(bp + k0);
      const short* wb = wo_a + tap * 256 + part * 64 + k0;
#pragma unroll
      for (int mt = 0; mt < 7; ++mt) {
        s16x8 af = *(const s16x8*)(wb + (size_t)(16 * mt + l15) * 2304);
        acc[mt] = __builtin_amdgcn_mfma_f32_16x16x32_bf16(af, bf_f, acc[mt], 0, 0, 0);
      }
    }
  }

  short* wp = wpart + ((size_t)part * 8 + b) * 108 * 4096;
#pragma unroll
  for (int mt = 0; mt < 7; ++mt) {
#pragma unroll
    for (int r = 0; r < 4; ++r) {
      int co = 16 * mt + quad * 4 + r;
      if (co < 108) {
        float v = acc[mt][r] + (part == 0 ? b_off[co] : 0.f);
        wp[(size_t)co * 4096 + h * 64 + nb] = (short)bfr(v);
      }
    }
  }
}

// DCN, bf16 MFMA, XCD-pinned (b,g) groups. Gather from x2: per thread-tap
// 4 corners x 2 chunks x 16B vector loads; bilinear combine in f32.
__global__ __launch_bounds__(256) void k_dcn(
    const short* __restrict__ x2, const short* __restrict__ wpart,
    const short* __restrict__ wd_a, const float* __restrict__ b_dcn,
    float* __restrict__ dcn) {
  __shared__ short p_s[64 * 68];

  int bi = blockIdx.x;  // 2048
  int xcd = bi & 7;
  int j = bi >> 3;
  int grp = xcd * 4 + (j & 3);  // 0..31, pinned to xcd
  int h = j >> 2;               // 0..63
  int b = grp >> 2, g = grp & 3;
  int tid = threadIdx.x;
  int px = tid & 63, iq = tid >> 6;
  int lane = tid & 63, wv = tid >> 6;
  int quad = lane >> 4, l15 = lane & 15;

  f32x4 zero4 = {0.f, 0.f, 0.f, 0.f};
  f32x4 acc[4];
#pragma unroll
  for (int i = 0; i < 4; ++i) acc[i] = zero4;

  const short* x2g = x2 + (size_t)(b * 32 + g * 8) * 34848;
  int sp = h * 64 + px;

  for (int c = 0; c < 9; ++c) {
    // offset/mask params for (tap c, column px): fold 4 bf16 partials
    int co_y = (g * 9 + c) * 2;
    float oy = 0.f, ox = 0.f, mz = 0.f;
#pragma unroll
    for (int p4 = 0; p4 < 4; ++p4) {
      const short* wp = wpart + ((size_t)p4 * 8 + b) * 108 * 4096;
      oy += bff((unsigned short)wp[(size_t)co_y * 4096 + sp]);
      ox += bff((unsigned short)wp[(size_t)(co_y + 1) * 4096 + sp]);
      mz += bff((unsigned short)wp[(size_t)(72 + g * 9 + c) * 4096 + sp]);
    }
    float m = 1.f / (1.f + __expf(-mz));
    float py = (float)h + (float)(c / 3 - 1) + oy;
    float pxf = (float)px + (float)(c % 3 - 1) + ox;
    float y0 = floorf(py), x0 = floorf(pxf);
    float wy1 = py - y0, wy0 = 1.f - wy1;
    float wx1 = pxf - x0, wx0 = 1.f - wx1;
    int y0i = (int)y0, x0i = (int)x0;
    int y1i = y0i + 1, x1i = x0i + 1;
    bool vy0 = (y0i >= 0) & (y0i < 64), vy1 = (y1i >= 0) & (y1i < 64);
    bool vx0 = (x0i >= 0) & (x0i < 64), vx1 = (x1i >= 0) & (x1i < 64);
    int cy0 = min(max(y0i, 0), 63) + 1, cy1 = min(max(y1i, 0), 63) + 1;
    int cx0 = min(max(x0i, 0), 63) + 1, cx1 = min(max(x1i, 0), 63) + 1;
    int4 id = make_int4(cy0 * 66 + cx0, cy0 * 66 + cx1,
                        cy1 * 66 + cx0, cy1 * 66 + cx1);
    float4 wt = make_float4((vy0 && vx0) ? wy0 * wx0 * m : 0.f,
                            (vy0 && vx1) ? wy0 * wx1 * m : 0.f,
                            (vy1 && vx0) ? wy1 * wx0 * m : 0.f,
                            (vy1 && vx1) ? wy1 * wx1 * m : 0.f);
#pragma unroll
    for (int jj = 0; jj < 2; ++jj) {
      int cc = iq * 2 + jj;
      const short* pl = x2g + (size_t)cc * 34848;
      s16x8 a00 = ld8(pl + (size_t)id.x * 8);
      s16x8 a01 = ld8(pl + (size_t)id.y * 8);
      s16x8 a10 = ld8(pl + (size_t)id.z * 8);
      s16x8 a11 = ld8(pl + (size_t)id.w * 8);
      s16x4 o0, o1;
#pragma unroll
      for (int i = 0; i < 8; ++i) {
        float v = wt.x * bf(a00[i]) + wt.y * bf(a01[i]) +
                  wt.z * bf(a10[i]) + wt.w * bf(a11[i]);
        if (i < 4) o0[i] = (short)bfr(v);
        else o1[i - 4] = (short)bfr(v);
      }
      *(s16x4*)&p_s[px * 68 + iq * 16 + jj * 8] = o0;
      *(s16x4*)&p_s[px * 68 + iq * 16 + jj * 8 + 4] = o1;
    }
    __syncthreads();
#pragma unroll
    for (int s = 0; s < 2; ++s) {
      int k0 = 32 * s + quad * 8;
      s16x8 bf_f = ld8(&p_s[(16 * wv + l15) * 68 + k0]);
      const short* whb = wd_a + (size_t)g * 36864 + c * 64 + k0;
#pragma unroll
      for (int mt = 0; mt < 4; ++mt) {
        s16x8 af = *(const s16x8*)(whb + (size_t)(16 * mt + l15) * 576);
        acc[mt] = __builtin_amdgcn_mfma_f32_16x16x32_bf16(af, bf_f, acc[mt], 0, 0, 0);
      }
    }
    __syncthreads();
  }

  int nb = 16 * wv + l15;
#pragma unroll
  for (int mt = 0; mt < 4; ++mt) {
#pragma unroll
    for (int r = 0; r < 4; ++r) {
      int co = 16 * mt + quad * 4 + r;
      dcn[(((size_t)b * 256 + g * 64 + co) * 64 + h) * 64 + nb] =
          acc[mt][r] + b_dcn[g * 64 + co];
    }
  }
}

// LayerNorm over C + sigmoid + gate. dcn == out (in-place safe).
__global__ __launch_bounds__(256) void k_ln(
    const float* __restrict__ dcn, const float* __restrict__ x,
    const float* __restrict__ gamma, const float* __restrict__ beta,
    float* __restrict__ out) {
  __shared__ float red_s[4][64];
  __shared__ float red_q[4][64];
  int px = threadIdx.x & 63;
  int part = threadIdx.x >> 6;
  int p = blockIdx.x * 64 + px;  // 32768 pixels
  int b = p >> 12, hw = p & 4095;
  const float* ob = dcn + (size_t)b * 256 * 4096 + hw;
  const float* xb = x + (size_t)b * 256 * 4096 + hw;
  float* yb = out + (size_t)b * 256 * 4096 + hw;
  int c0 = part * 64;
  float s = 0.f, s2 = 0.f;
  for (int c = c0; c < c0 + 64; ++c) {
    float v = ob[c * 4096];
    s += v;
    s2 += v * v;
  }
  red_s[part][px] = s;
  red_q[part][px] = s2;
  __syncthreads();
  s = red_s[0][px] + red_s[1][px] + red_s[2][px] + red_s[3][px];
  s2 = red_q[0][px] + red_q[1][px] + red_q[2][px] + red_q[3][px];
  float mu = s * (1.f / 256.f);
  float var = s2 * (1.f / 256.f) - mu * mu;
  float rs = rsqrtf(var + 1e-5f);
  for (int c = c0; c < c0 + 64; ++c) {
    float v = ob[c * 4096];
    float nrm = (v - mu) * rs * gamma[c] + beta[c];
    float attn = 1.f / (1.f + __expf(-nrm));
    yb[c * 4096] = xb[c * 4096] * attn;
  }
}

extern "C" void kernel_launch(void* const* d_in, const int* in_sizes, int n_in,
                              void* d_out, int out_size, void* d_ws,
                              size_t ws_size, hipStream_t stream) {
  const float* x = (const float*)d_in[0];
  const float* w_off = (const float*)d_in[1];
  const float* b_off = (const float*)d_in[2];
  const float* w_dcn = (const float*)d_in[3];
  const float* b_dcn = (const float*)d_in[4];
  const float* gamma = (const float*)d_in[5];
  const float* beta = (const float*)d_in[6];
  float* out = (float*)d_out;
  char* wsb = (char*)d_ws;

  short* wpart = (short*)wsb;              // 28,311,552 B
  short* wo_a = (short*)(wsb + 28311552);  // 516,096 B
  short* wd_a = (short*)(wsb + 28827648);  // 294,912 B
  short* x2 = (short*)(wsb + 29122560);    // 17,842,176 B
  float* dcnb = out;                       // d_out doubles as dcn scratch

  k_prep<<<1584, 256, 0, stream>>>(w_off, w_dcn, wo_a, wd_a);
  k_x2<<<4356, 256, 0, stream>>>(x, x2);
  k_offconv<<<2048, 256, 0, stream>>>(x2, wo_a, b_off, wpart);
  k_dcn<<<2048, 256, 0, stream>>>(x2, wpart, wd_a, b_dcn, dcnb);
  k_ln<<<512, 256, 0, stream>>>(dcnb, x, gamma, beta, out);
}

// Round 2
// 283.299 us; speedup vs baseline: 1.2068x; 1.2061x over previous
//
#include <hip/hip_runtime.h>
#include <math.h>

// B=8, C=256, H=W=64, G=4, K=3, KK=9, Cg=64
// Round 11: k_offconv goes multi-row. Each block computes 4 output rows
// (h0..h0+3) for one (part,b): stages the shared 6x66 input window (53.9 KB)
// once, then per (tap,s) loads af[7] weight fragments ONCE and reuses each
// across 4 row-MFMAs (MFMA:gather 1:1 -> 4:1; weight L2 gather traffic /4;
// grid 2048 -> 512 = exactly 2 blocks/CU). Accumulation order per output
// element unchanged (tap -> s) => bit-identical. All other kernels identical.
// ws layout (bytes):
//   wpart bf16 [4][8][108][4096] @ 0          (28,311,552)
//   wo_a  bf16 [112][2304]       @ 28,311,552 (516,096)   k = tap*256+ch
//   wd_a  bf16 [4][64][576]      @ 28,827,648 (294,912)   k = tap*64+cl
//   x2    bf16 [256][4356][8]    @ 29,122,560 (17,842,176)
// total 46,964,736 B (< proven 48.3 MB)

typedef __attribute__((ext_vector_type(4))) short s16x4;
typedef __attribute__((ext_vector_type(8))) short s16x8;
typedef __attribute__((ext_vector_type(4))) float f32x4;

union S8 { s16x8 v; s16x4 h[2]; };

__device__ __forceinline__ s16x8 ld8(const short* p) {
  S8 r;
  r.h[0] = *(const s16x4*)p;
  r.h[1] = *(const s16x4*)(p + 4);
  return r.v;
}

__device__ __forceinline__ unsigned short bfr(float v) {  // RNE to bf16
  unsigned u = __float_as_uint(v);
  u = (u + 0x7FFFu + ((u >> 16) & 1u)) >> 16;
  return (unsigned short)u;
}
__device__ __forceinline__ float bff(unsigned short s) {
  return __uint_as_float(((unsigned)s) << 16);
}
__device__ __forceinline__ float bf(short s) {
  return __uint_as_float(((unsigned)(unsigned short)s) << 16);
}

__global__ __launch_bounds__(256) void k_prep(
    const float* __restrict__ w_off, const float* __restrict__ w_dcn,
    short* __restrict__ wo_a, short* __restrict__ wd_a) {
  int i = blockIdx.x * 256 + threadIdx.x;
  const int n1 = 112 * 2304;
  if (i < n1) {
    int co = i / 2304, k = i % 2304;
    int tap = k >> 8, ch = k & 255;  // k = tap*256 + ch
    float v = (co < 108) ? w_off[(co * 256 + ch) * 9 + tap] : 0.f;
    wo_a[i] = (short)bfr(v);
  } else {
    int j = i - n1;  // exactly 147456 remaining threads (grid 1584*256)
    int g = j / 36864, r = j % 36864;
    int co = r / 576, k = r % 576;
    int kk = k >> 6, cl = k & 63;  // k = tap*64 + cl
    wd_a[j] = (short)bfr(w_dcn[((g * 64 + co) * 64 + cl) * 9 + kk]);
  }
}

// x -> chunked bf16 NHWC with zero halo.
// interior: thread = (b, c2, pixel); border: zero 16B slots.
__global__ __launch_bounds__(256) void k_x2(
    const float* __restrict__ x, short* __restrict__ x2) {
  int id = blockIdx.x * 256 + threadIdx.x;
  const int n1 = 8 * 32 * 4096;  // 1,048,576 interior items
  if (id < n1) {
    int pc = id & 4095;
    int c2 = (id >> 12) & 31;
    int b = id >> 17;
    int h = pc >> 6, w = pc & 63;
    const float* xp = x + ((size_t)(b * 256 + c2 * 8)) * 4096 + pc;
    short* o = x2 + ((size_t)(b * 32 + c2) * 4356 + (h + 1) * 66 + (w + 1)) * 8;
    s16x4 v0, v1;
#pragma unroll
    for (int i = 0; i < 4; ++i) {
      v0[i] = (short)bfr(xp[(size_t)i * 4096]);
      v1[i] = (short)bfr(xp[(size_t)(i + 4) * 4096]);
    }
    *(s16x4*)o = v0;
    *(s16x4*)(o + 4) = v1;
  } else {
    int j = id - n1;  // grid sized exactly: j < 256*260
    int plane = j / 260, r = j % 260;
    int h, w;
    if (r < 66) { h = 0; w = r; }
    else if (r < 132) { h = 65; w = r - 66; }
    else if (r < 196) { h = r - 131; w = 0; }
    else { h = r - 195; w = 65; }
    short* o = x2 + ((size_t)plane * 4356 + h * 66 + w) * 8;
    s16x4 z = {0, 0, 0, 0};
    *(s16x4*)o = z;
    *(s16x4*)(o + 4) = z;
  }
}

// Offset conv, bf16 MFMA, K-split by channel-quarter, XCD-pinned slices.
// Round 11: 4 output rows per block. Stage 6x66 window once; per (tap,s)
// load af[7] once and apply to 4 rows' B-fragments (weight reuse x4).
__global__ __launch_bounds__(256) void k_offconv(
    const short* __restrict__ x2, const short* __restrict__ wo_a,
    const float* __restrict__ b_off, short* __restrict__ wpart) {
  __shared__ short p_s[6 * 66 * 68];  // [winrow 0..5][pix 0..65][64 ch + 4 pad]
  int bi = blockIdx.x;  // 512
  int xcd = bi & 7;
  int j = bi >> 3;                // 0..63
  int slice = xcd * 4 + (j & 3);  // 0..31, pinned to xcd
  int h0 = (j >> 2) * 4;          // 0,4,...,60
  int part = slice >> 3, b = slice & 7;
  int tid = threadIdx.x;
  int lane = tid & 63, wv = tid >> 6;
  int quad = lane >> 4, l15 = lane & 15;

  f32x4 zero4 = {0.f, 0.f, 0.f, 0.f};
  f32x4 acc[7][4];
#pragma unroll
  for (int i = 0; i < 7; ++i)
#pragma unroll
    for (int r = 0; r < 4; ++r) acc[i][r] = zero4;

  // planes for this block's 64 channels: (b*32 + part*8 + ck), ck = 0..7
  const short* x2b = x2 + (size_t)(b * 32 + part * 8) * 34848;

  // Stage the 6-row x 66-col window once: 3168 x 16B chunks (12.4/thread).
  // Window row w = padded row h0+w (covers outputs h0..h0+3, taps ky 0..2).
  for (int it = tid; it < 3168; it += 256) {
    int ck = it / 396;
    int rp = it - ck * 396;  // rp = winrow*66 + pix
    const short* src = x2b + (size_t)ck * 34848 + ((size_t)h0 * 66 + rp) * 8;
    S8 v;
    v.v = *(const s16x8*)src;  // 16B aligned
    short* dst = &p_s[rp * 68 + ck * 8];
    *(s16x4*)dst = v.h[0];
    *(s16x4*)(dst + 4) = v.h[1];
  }
  __syncthreads();

  int nb = 16 * wv + l15;  // output column this lane owns (B-fragment row)
#pragma unroll
  for (int tap = 0; tap < 9; ++tap) {
    int ky = tap / 3, kx = tap % 3;
#pragma unroll
    for (int s = 0; s < 2; ++s) {
      int k0 = 32 * s + quad * 8;
      const short* wb = wo_a + tap * 256 + part * 64 + k0;
      s16x8 af[7];
#pragma unroll
      for (int mt = 0; mt < 7; ++mt)
        af[mt] = *(const s16x8*)(wb + (size_t)(16 * mt + l15) * 2304);
#pragma unroll
      for (int r = 0; r < 4; ++r) {
        // output row h0+r, tap (ky,kx): padded (h0+r+ky, nb+kx) = winrow r+ky
        s16x8 bf_f = ld8(&p_s[((r + ky) * 66 + nb + kx) * 68 + k0]);
#pragma unroll
        for (int mt = 0; mt < 7; ++mt)
          acc[mt][r] =
              __builtin_amdgcn_mfma_f32_16x16x32_bf16(af[mt], bf_f, acc[mt][r], 0, 0, 0);
      }
    }
  }

  short* wp = wpart + ((size_t)part * 8 + b) * 108 * 4096;
#pragma unroll
  for (int mt = 0; mt < 7; ++mt) {
#pragma unroll
    for (int rr = 0; rr < 4; ++rr) {
#pragma unroll
      for (int r = 0; r < 4; ++r) {
        int co = 16 * mt + quad * 4 + r;
        if (co < 108) {
          float v = acc[mt][rr][r] + (part == 0 ? b_off[co] : 0.f);
          wp[(size_t)co * 4096 + (h0 + rr) * 64 + nb] = (short)bfr(v);
        }
      }
    }
  }
}

// DCN, bf16 MFMA, XCD-pinned (b,g) groups. Gather from x2: per thread-tap
// 4 corners x 2 chunks x 16B vector loads; bilinear combine in f32.
__global__ __launch_bounds__(256) void k_dcn(
    const short* __restrict__ x2, const short* __restrict__ wpart,
    const short* __restrict__ wd_a, const float* __restrict__ b_dcn,
    float* __restrict__ dcn) {
  __shared__ short p_s[64 * 68];

  int bi = blockIdx.x;  // 2048
  int xcd = bi & 7;
  int j = bi >> 3;
  int grp = xcd * 4 + (j & 3);  // 0..31, pinned to xcd
  int h = j >> 2;               // 0..63
  int b = grp >> 2, g = grp & 3;
  int tid = threadIdx.x;
  int px = tid & 63, iq = tid >> 6;
  int lane = tid & 63, wv = tid >> 6;
  int quad = lane >> 4, l15 = lane & 15;

  f32x4 zero4 = {0.f, 0.f, 0.f, 0.f};
  f32x4 acc[4];
#pragma unroll
  for (int i = 0; i < 4; ++i) acc[i] = zero4;

  const short* x2g = x2 + (size_t)(b * 32 + g * 8) * 34848;
  int sp = h * 64 + px;

  for (int c = 0; c < 9; ++c) {
    // offset/mask params for (tap c, column px): fold 4 bf16 partials
    int co_y = (g * 9 + c) * 2;
    float oy = 0.f, ox = 0.f, mz = 0.f;
#pragma unroll
    for (int p4 = 0; p4 < 4; ++p4) {
      const short* wp = wpart + ((size_t)p4 * 8 + b) * 108 * 4096;
      oy += bff((unsigned short)wp[(size_t)co_y * 4096 + sp]);
      ox += bff((unsigned short)wp[(size_t)(co_y + 1) * 4096 + sp]);
      mz += bff((unsigned short)wp[(size_t)(72 + g * 9 + c) * 4096 + sp]);
    }
    float m = 1.f / (1.f + __expf(-mz));
    float py = (float)h + (float)(c / 3 - 1) + oy;
    float pxf = (float)px + (float)(c % 3 - 1) + ox;
    float y0 = floorf(py), x0 = floorf(pxf);
    float wy1 = py - y0, wy0 = 1.f - wy1;
    float wx1 = pxf - x0, wx0 = 1.f - wx1;
    int y0i = (int)y0, x0i = (int)x0;
    int y1i = y0i + 1, x1i = x0i + 1;
    bool vy0 = (y0i >= 0) & (y0i < 64), vy1 = (y1i >= 0) & (y1i < 64);
    bool vx0 = (x0i >= 0) & (x0i < 64), vx1 = (x1i >= 0) & (x1i < 64);
    int cy0 = min(max(y0i, 0), 63) + 1, cy1 = min(max(y1i, 0), 63) + 1;
    int cx0 = min(max(x0i, 0), 63) + 1, cx1 = min(max(x1i, 0), 63) + 1;
    int4 id = make_int4(cy0 * 66 + cx0, cy0 * 66 + cx1,
                        cy1 * 66 + cx0, cy1 * 66 + cx1);
    float4 wt = make_float4((vy0 && vx0) ? wy0 * wx0 * m : 0.f,
                            (vy0 && vx1) ? wy0 * wx1 * m : 0.f,
                            (vy1 && vx0) ? wy1 * wx0 * m : 0.f,
                            (vy1 && vx1) ? wy1 * wx1 * m : 0.f);
#pragma unroll
    for (int jj = 0; jj < 2; ++jj) {
      int cc = iq * 2 + jj;
      const short* pl = x2g + (size_t)cc * 34848;
      s16x8 a00 = ld8(pl + (size_t)id.x * 8);
      s16x8 a01 = ld8(pl + (size_t)id.y * 8);
      s16x8 a10 = ld8(pl + (size_t)id.z * 8);
      s16x8 a11 = ld8(pl + (size_t)id.w * 8);
      s16x4 o0, o1;
#pragma unroll
      for (int i = 0; i < 8; ++i) {
        float v = wt.x * bf(a00[i]) + wt.y * bf(a01[i]) +
                  wt.z * bf(a10[i]) + wt.w * bf(a11[i]);
        if (i < 4) o0[i] = (short)bfr(v);
        else o1[i - 4] = (short)bfr(v);
      }
      *(s16x4*)&p_s[px * 68 + iq * 16 + jj * 8] = o0;
      *(s16x4*)&p_s[px * 68 + iq * 16 + jj * 8 + 4] = o1;
    }
    __syncthreads();
#pragma unroll
    for (int s = 0; s < 2; ++s) {
      int k0 = 32 * s + quad * 8;
      s16x8 bf_f = ld8(&p_s[(16 * wv + l15) * 68 + k0]);
      const short* whb = wd_a + (size_t)g * 36864 + c * 64 + k0;
#pragma unroll
      for (int mt = 0; mt < 4; ++mt) {
        s16x8 af = *(const s16x8*)(whb + (size_t)(16 * mt + l15) * 576);
        acc[mt] = __builtin_amdgcn_mfma_f32_16x16x32_bf16(af, bf_f, acc[mt], 0, 0, 0);
      }
    }
    __syncthreads();
  }

  int nb = 16 * wv + l15;
#pragma unroll
  for (int mt = 0; mt < 4; ++mt) {
#pragma unroll
    for (int r = 0; r < 4; ++r) {
      int co = 16 * mt + quad * 4 + r;
      dcn[(((size_t)b * 256 + g * 64 + co) * 64 + h) * 64 + nb] =
          acc[mt][r] + b_dcn[g * 64 + co];
    }
  }
}

// LayerNorm over C + sigmoid + gate. dcn == out (in-place safe).
__global__ __launch_bounds__(256) void k_ln(
    const float* __restrict__ dcn, const float* __restrict__ x,
    const float* __restrict__ gamma, const float* __restrict__ beta,
    float* __restrict__ out) {
  __shared__ float red_s[4][64];
  __shared__ float red_q[4][64];
  int px = threadIdx.x & 63;
  int part = threadIdx.x >> 6;
  int p = blockIdx.x * 64 + px;  // 32768 pixels
  int b = p >> 12, hw = p & 4095;
  const float* ob = dcn + (size_t)b * 256 * 4096 + hw;
  const float* xb = x + (size_t)b * 256 * 4096 + hw;
  float* yb = out + (size_t)b * 256 * 4096 + hw;
  int c0 = part * 64;
  float s = 0.f, s2 = 0.f;
  for (int c = c0; c < c0 + 64; ++c) {
    float v = ob[c * 4096];
    s += v;
    s2 += v * v;
  }
  red_s[part][px] = s;
  red_q[part][px] = s2;
  __syncthreads();
  s = red_s[0][px] + red_s[1][px] + red_s[2][px] + red_s[3][px];
  s2 = red_q[0][px] + red_q[1][px] + red_q[2][px] + red_q[3][px];
  float mu = s * (1.f / 256.f);
  float var = s2 * (1.f / 256.f) - mu * mu;
  float rs = rsqrtf(var + 1e-5f);
  for (int c = c0; c < c0 + 64; ++c) {
    float v = ob[c * 4096];
    float nrm = (v - mu) * rs * gamma[c] + beta[c];
    float attn = 1.f / (1.f + __expf(-nrm));
    yb[c * 4096] = xb[c * 4096] * attn;
  }
}

extern "C" void kernel_launch(void* const* d_in, const int* in_sizes, int n_in,
                              void* d_out, int out_size, void* d_ws,
                              size_t ws_size, hipStream_t stream) {
  const float* x = (const float*)d_in[0];
  const float* w_off = (const float*)d_in[1];
  const float* b_off = (const float*)d_in[2];
  const float* w_dcn = (const float*)d_in[3];
  const float* b_dcn = (const float*)d_in[4];
  const float* gamma = (const float*)d_in[5];
  const float* beta = (const float*)d_in[6];
  float* out = (float*)d_out;
  char* wsb = (char*)d_ws;

  short* wpart = (short*)wsb;              // 28,311,552 B
  short* wo_a = (short*)(wsb + 28311552);  // 516,096 B
  short* wd_a = (short*)(wsb + 28827648);  // 294,912 B
  short* x2 = (short*)(wsb + 29122560);    // 17,842,176 B
  float* dcnb = out;                       // d_out doubles as dcn scratch

  k_prep<<<1584, 256, 0, stream>>>(w_off, w_dcn, wo_a, wd_a);
  k_x2<<<4356, 256, 0, stream>>>(x, x2);
  k_offconv<<<512, 256, 0, stream>>>(x2, wo_a, b_off, wpart);
  k_dcn<<<2048, 256, 0, stream>>>(x2, wpart, wd_a, b_dcn, dcnb);
  k_ln<<<512, 256, 0, stream>>>(dcnb, x, gamma, beta, out);
}

// Round 3
// 276.002 us; speedup vs baseline: 1.2387x; 1.0264x over previous
//
#include <hip/hip_runtime.h>
#include <math.h>

// B=8, C=256, H=W=64, G=4, K=3, KK=9, Cg=64
// Round 12: k_dcn restructured for wave decoupling.
//  - Phase A: offset/mask params (py,pxf,m) computed ONCE per (tap,px) by a
//    deduplicated 576-item sweep (was 4x redundant across iq), stored in LDS.
//  - Tap loop: lane (quad=chunk-pair, l15=pixel) of wave wv samples pixel
//    16wv+l15 -- exactly the pixels wave wv consumes as MFMA B-fragments.
//    Sample exchange is wave-private (same-wave ds_write -> ds_read, DS-pipe
//    ordered): ALL 18 __syncthreads removed from the tap loop; waves overlap
//    gather/VALU/MFMA phases freely.
//  Numerics per output element unchanged (same formulas, same accumulation
//  order) => bit-identical. k_offconv keeps round-11 multi-row form.
// ws layout (bytes):
//   wpart bf16 [4][8][108][4096] @ 0          (28,311,552)
//   wo_a  bf16 [112][2304]       @ 28,311,552 (516,096)   k = tap*256+ch
//   wd_a  bf16 [4][64][576]      @ 28,827,648 (294,912)   k = tap*64+cl
//   x2    bf16 [256][4356][8]    @ 29,122,560 (17,842,176)
// total 46,964,736 B (< proven 48.3 MB)

typedef __attribute__((ext_vector_type(4))) short s16x4;
typedef __attribute__((ext_vector_type(8))) short s16x8;
typedef __attribute__((ext_vector_type(4))) float f32x4;

union S8 { s16x8 v; s16x4 h[2]; };

__device__ __forceinline__ s16x8 ld8(const short* p) {
  S8 r;
  r.h[0] = *(const s16x4*)p;
  r.h[1] = *(const s16x4*)(p + 4);
  return r.v;
}

__device__ __forceinline__ unsigned short bfr(float v) {  // RNE to bf16
  unsigned u = __float_as_uint(v);
  u = (u + 0x7FFFu + ((u >> 16) & 1u)) >> 16;
  return (unsigned short)u;
}
__device__ __forceinline__ float bff(unsigned short s) {
  return __uint_as_float(((unsigned)s) << 16);
}
__device__ __forceinline__ float bf(short s) {
  return __uint_as_float(((unsigned)(unsigned short)s) << 16);
}

__global__ __launch_bounds__(256) void k_prep(
    const float* __restrict__ w_off, const float* __restrict__ w_dcn,
    short* __restrict__ wo_a, short* __restrict__ wd_a) {
  int i = blockIdx.x * 256 + threadIdx.x;
  const int n1 = 112 * 2304;
  if (i < n1) {
    int co = i / 2304, k = i % 2304;
    int tap = k >> 8, ch = k & 255;  // k = tap*256 + ch
    float v = (co < 108) ? w_off[(co * 256 + ch) * 9 + tap] : 0.f;
    wo_a[i] = (short)bfr(v);
  } else {
    int j = i - n1;  // exactly 147456 remaining threads (grid 1584*256)
    int g = j / 36864, r = j % 36864;
    int co = r / 576, k = r % 576;
    int kk = k >> 6, cl = k & 63;  // k = tap*64 + cl
    wd_a[j] = (short)bfr(w_dcn[((g * 64 + co) * 64 + cl) * 9 + kk]);
  }
}

// x -> chunked bf16 NHWC with zero halo.
// interior: thread = (b, c2, pixel); border: zero 16B slots.
__global__ __launch_bounds__(256) void k_x2(
    const float* __restrict__ x, short* __restrict__ x2) {
  int id = blockIdx.x * 256 + threadIdx.x;
  const int n1 = 8 * 32 * 4096;  // 1,048,576 interior items
  if (id < n1) {
    int pc = id & 4095;
    int c2 = (id >> 12) & 31;
    int b = id >> 17;
    int h = pc >> 6, w = pc & 63;
    const float* xp = x + ((size_t)(b * 256 + c2 * 8)) * 4096 + pc;
    short* o = x2 + ((size_t)(b * 32 + c2) * 4356 + (h + 1) * 66 + (w + 1)) * 8;
    s16x4 v0, v1;
#pragma unroll
    for (int i = 0; i < 4; ++i) {
      v0[i] = (short)bfr(xp[(size_t)i * 4096]);
      v1[i] = (short)bfr(xp[(size_t)(i + 4) * 4096]);
    }
    *(s16x4*)o = v0;
    *(s16x4*)(o + 4) = v1;
  } else {
    int j = id - n1;  // grid sized exactly: j < 256*260
    int plane = j / 260, r = j % 260;
    int h, w;
    if (r < 66) { h = 0; w = r; }
    else if (r < 132) { h = 65; w = r - 66; }
    else if (r < 196) { h = r - 131; w = 0; }
    else { h = r - 195; w = 65; }
    short* o = x2 + ((size_t)plane * 4356 + h * 66 + w) * 8;
    s16x4 z = {0, 0, 0, 0};
    *(s16x4*)o = z;
    *(s16x4*)(o + 4) = z;
  }
}

// Offset conv, bf16 MFMA, K-split by channel-quarter, XCD-pinned slices.
// Round 11 form: 4 output rows per block; stage 6x66 window once; per (tap,s)
// load af[7] once and apply to 4 rows' B-fragments (weight reuse x4).
__global__ __launch_bounds__(256) void k_offconv(
    const short* __restrict__ x2, const short* __restrict__ wo_a,
    const float* __restrict__ b_off, short* __restrict__ wpart) {
  __shared__ short p_s[6 * 66 * 68];  // [winrow 0..5][pix 0..65][64 ch + 4 pad]
  int bi = blockIdx.x;  // 512
  int xcd = bi & 7;
  int j = bi >> 3;                // 0..63
  int slice = xcd * 4 + (j & 3);  // 0..31, pinned to xcd
  int h0 = (j >> 2) * 4;          // 0,4,...,60
  int part = slice >> 3, b = slice & 7;
  int tid = threadIdx.x;
  int lane = tid & 63, wv = tid >> 6;
  int quad = lane >> 4, l15 = lane & 15;

  f32x4 zero4 = {0.f, 0.f, 0.f, 0.f};
  f32x4 acc[7][4];
#pragma unroll
  for (int i = 0; i < 7; ++i)
#pragma unroll
    for (int r = 0; r < 4; ++r) acc[i][r] = zero4;

  // planes for this block's 64 channels: (b*32 + part*8 + ck), ck = 0..7
  const short* x2b = x2 + (size_t)(b * 32 + part * 8) * 34848;

  // Stage the 6-row x 66-col window once: 3168 x 16B chunks (12.4/thread).
  for (int it = tid; it < 3168; it += 256) {
    int ck = it / 396;
    int rp = it - ck * 396;  // rp = winrow*66 + pix
    const short* src = x2b + (size_t)ck * 34848 + ((size_t)h0 * 66 + rp) * 8;
    S8 v;
    v.v = *(const s16x8*)src;  // 16B aligned
    short* dst = &p_s[rp * 68 + ck * 8];
    *(s16x4*)dst = v.h[0];
    *(s16x4*)(dst + 4) = v.h[1];
  }
  __syncthreads();

  int nb = 16 * wv + l15;  // output column this lane owns (B-fragment row)
#pragma unroll
  for (int tap = 0; tap < 9; ++tap) {
    int ky = tap / 3, kx = tap % 3;
#pragma unroll
    for (int s = 0; s < 2; ++s) {
      int k0 = 32 * s + quad * 8;
      const short* wb = wo_a + tap * 256 + part * 64 + k0;
      s16x8 af[7];
#pragma unroll
      for (int mt = 0; mt < 7; ++mt)
        af[mt] = *(const s16x8*)(wb + (size_t)(16 * mt + l15) * 2304);
#pragma unroll
      for (int r = 0; r < 4; ++r) {
        // output row h0+r, tap (ky,kx): padded (h0+r+ky, nb+kx) = winrow r+ky
        s16x8 bf_f = ld8(&p_s[((r + ky) * 66 + nb + kx) * 68 + k0]);
#pragma unroll
        for (int mt = 0; mt < 7; ++mt)
          acc[mt][r] =
              __builtin_amdgcn_mfma_f32_16x16x32_bf16(af[mt], bf_f, acc[mt][r], 0, 0, 0);
      }
    }
  }

  short* wp = wpart + ((size_t)part * 8 + b) * 108 * 4096;
#pragma unroll
  for (int mt = 0; mt < 7; ++mt) {
#pragma unroll
    for (int rr = 0; rr < 4; ++rr) {
#pragma unroll
      for (int r = 0; r < 4; ++r) {
        int co = 16 * mt + quad * 4 + r;
        if (co < 108) {
          float v = acc[mt][rr][r] + (part == 0 ? b_off[co] : 0.f);
          wp[(size_t)co * 4096 + (h0 + rr) * 64 + nb] = (short)bfr(v);
        }
      }
    }
  }
}

// DCN, bf16 MFMA, XCD-pinned (b,g) groups.
// Round 12: barrier-free tap loop. Lane (quad, l15) of wave wv samples pixel
// 16wv+l15, chunks 2*quad..2*quad+1; exchange via wave-private LDS rows.
// Offset params deduplicated in phase A (one __syncthreads total).
__global__ __launch_bounds__(256) void k_dcn(
    const short* __restrict__ x2, const short* __restrict__ wpart,
    const short* __restrict__ wd_a, const float* __restrict__ b_dcn,
    float* __restrict__ dcn) {
  __shared__ short p_s[64 * 68];   // [pixel][64ch + 4 pad], rows wave-private
  __shared__ float4 prm[9][64];    // (py, pxf, m, -) per (tap, px)

  int bi = blockIdx.x;  // 2048
  int xcd = bi & 7;
  int j = bi >> 3;
  int grp = xcd * 4 + (j & 3);  // 0..31, pinned to xcd
  int h = j >> 2;               // 0..63
  int b = grp >> 2, g = grp & 3;
  int tid = threadIdx.x;
  int lane = tid & 63, wv = tid >> 6;
  int quad = lane >> 4, l15 = lane & 15;
  int px = 16 * wv + l15;  // pixel this lane samples AND owns as output column

  f32x4 zero4 = {0.f, 0.f, 0.f, 0.f};
  f32x4 acc[4];
#pragma unroll
  for (int i = 0; i < 4; ++i) acc[i] = zero4;

  const short* x2g = x2 + (size_t)(b * 32 + g * 8) * 34848;

  // ---- Phase A: offset/mask params, deduplicated (was 4x redundant) ----
  for (int i = tid; i < 576; i += 256) {
    int c = i >> 6, pxa = i & 63;
    int sp = h * 64 + pxa;
    int co_y = (g * 9 + c) * 2;
    float oy = 0.f, ox = 0.f, mz = 0.f;
#pragma unroll
    for (int p4 = 0; p4 < 4; ++p4) {
      const short* wp = wpart + ((size_t)p4 * 8 + b) * 108 * 4096;
      oy += bff((unsigned short)wp[(size_t)co_y * 4096 + sp]);
      ox += bff((unsigned short)wp[(size_t)(co_y + 1) * 4096 + sp]);
      mz += bff((unsigned short)wp[(size_t)(72 + g * 9 + c) * 4096 + sp]);
    }
    float m = 1.f / (1.f + __expf(-mz));
    float py = (float)h + (float)(c / 3 - 1) + oy;
    float pxf = (float)pxa + (float)(c % 3 - 1) + ox;
    prm[c][pxa] = make_float4(py, pxf, m, 0.f);
  }
  __syncthreads();  // the only block-wide barrier

  // ---- Tap loop: no barriers; waves fully decoupled ----
  for (int c = 0; c < 9; ++c) {
    float4 pr = prm[c][px];
    float py = pr.x, pxf = pr.y, m = pr.z;
    float y0 = floorf(py), x0 = floorf(pxf);
    float wy1 = py - y0, wy0 = 1.f - wy1;
    float wx1 = pxf - x0, wx0 = 1.f - wx1;
    int y0i = (int)y0, x0i = (int)x0;
    int y1i = y0i + 1, x1i = x0i + 1;
    bool vy0 = (y0i >= 0) & (y0i < 64), vy1 = (y1i >= 0) & (y1i < 64);
    bool vx0 = (x0i >= 0) & (x0i < 64), vx1 = (x1i >= 0) & (x1i < 64);
    int cy0 = min(max(y0i, 0), 63) + 1, cy1 = min(max(y1i, 0), 63) + 1;
    int cx0 = min(max(x0i, 0), 63) + 1, cx1 = min(max(x1i, 0), 63) + 1;
    int4 id = make_int4(cy0 * 66 + cx0, cy0 * 66 + cx1,
                        cy1 * 66 + cx0, cy1 * 66 + cx1);
    float4 wt = make_float4((vy0 && vx0) ? wy0 * wx0 * m : 0.f,
                            (vy0 && vx1) ? wy0 * wx1 * m : 0.f,
                            (vy1 && vx0) ? wy1 * wx0 * m : 0.f,
                            (vy1 && vx1) ? wy1 * wx1 * m : 0.f);
#pragma unroll
    for (int jj = 0; jj < 2; ++jj) {
      int cc = 2 * quad + jj;  // chunk-pair owned by this lane
      const short* pl = x2g + (size_t)cc * 34848;
      s16x8 a00 = ld8(pl + (size_t)id.x * 8);
      s16x8 a01 = ld8(pl + (size_t)id.y * 8);
      s16x8 a10 = ld8(pl + (size_t)id.z * 8);
      s16x8 a11 = ld8(pl + (size_t)id.w * 8);
      s16x4 o0, o1;
#pragma unroll
      for (int i = 0; i < 8; ++i) {
        float v = wt.x * bf(a00[i]) + wt.y * bf(a01[i]) +
                  wt.z * bf(a10[i]) + wt.w * bf(a11[i]);
        if (i < 4) o0[i] = (short)bfr(v);
        else o1[i - 4] = (short)bfr(v);
      }
      *(s16x4*)&p_s[px * 68 + cc * 8] = o0;
      *(s16x4*)&p_s[px * 68 + cc * 8 + 4] = o1;
    }
    // wave-private exchange: rows 16wv..16wv+15 written and read only by
    // wave wv; same-wave DS ordering makes this safe without a barrier.
#pragma unroll
    for (int s = 0; s < 2; ++s) {
      int k0 = 32 * s + quad * 8;
      s16x8 bf_f = ld8(&p_s[px * 68 + k0]);
      const short* whb = wd_a + (size_t)g * 36864 + c * 64 + k0;
#pragma unroll
      for (int mt = 0; mt < 4; ++mt) {
        s16x8 af = *(const s16x8*)(whb + (size_t)(16 * mt + l15) * 576);
        acc[mt] = __builtin_amdgcn_mfma_f32_16x16x32_bf16(af, bf_f, acc[mt], 0, 0, 0);
      }
    }
  }

  int nb = px;
#pragma unroll
  for (int mt = 0; mt < 4; ++mt) {
#pragma unroll
    for (int r = 0; r < 4; ++r) {
      int co = 16 * mt + quad * 4 + r;
      dcn[(((size_t)b * 256 + g * 64 + co) * 64 + h) * 64 + nb] =
          acc[mt][r] + b_dcn[g * 64 + co];
    }
  }
}

// LayerNorm over C + sigmoid + gate. dcn == out (in-place safe).
__global__ __launch_bounds__(256) void k_ln(
    const float* __restrict__ dcn, const float* __restrict__ x,
    const float* __restrict__ gamma, const float* __restrict__ beta,
    float* __restrict__ out) {
  __shared__ float red_s[4][64];
  __shared__ float red_q[4][64];
  int px = threadIdx.x & 63;
  int part = threadIdx.x >> 6;
  int p = blockIdx.x * 64 + px;  // 32768 pixels
  int b = p >> 12, hw = p & 4095;
  const float* ob = dcn + (size_t)b * 256 * 4096 + hw;
  const float* xb = x + (size_t)b * 256 * 4096 + hw;
  float* yb = out + (size_t)b * 256 * 4096 + hw;
  int c0 = part * 64;
  float s = 0.f, s2 = 0.f;
  for (int c = c0; c < c0 + 64; ++c) {
    float v = ob[c * 4096];
    s += v;
    s2 += v * v;
  }
  red_s[part][px] = s;
  red_q[part][px] = s2;
  __syncthreads();
  s = red_s[0][px] + red_s[1][px] + red_s[2][px] + red_s[3][px];
  s2 = red_q[0][px] + red_q[1][px] + red_q[2][px] + red_q[3][px];
  float mu = s * (1.f / 256.f);
  float var = s2 * (1.f / 256.f) - mu * mu;
  float rs = rsqrtf(var + 1e-5f);
  for (int c = c0; c < c0 + 64; ++c) {
    float v = ob[c * 4096];
    float nrm = (v - mu) * rs * gamma[c] + beta[c];
    float attn = 1.f / (1.f + __expf(-nrm));
    yb[c * 4096] = xb[c * 4096] * attn;
  }
}

extern "C" void kernel_launch(void* const* d_in, const int* in_sizes, int n_in,
                              void* d_out, int out_size, void* d_ws,
                              size_t ws_size, hipStream_t stream) {
  const float* x = (const float*)d_in[0];
  const float* w_off = (const float*)d_in[1];
  const float* b_off = (const float*)d_in[2];
  const float* w_dcn = (const float*)d_in[3];
  const float* b_dcn = (const float*)d_in[4];
  const float* gamma = (const float*)d_in[5];
  const float* beta = (const float*)d_in[6];
  float* out = (float*)d_out;
  char* wsb = (char*)d_ws;

  short* wpart = (short*)wsb;              // 28,311,552 B
  short* wo_a = (short*)(wsb + 28311552);  // 516,096 B
  short* wd_a = (short*)(wsb + 28827648);  // 294,912 B
  short* x2 = (short*)(wsb + 29122560);    // 17,842,176 B
  float* dcnb = out;                       // d_out doubles as dcn scratch

  k_prep<<<1584, 256, 0, stream>>>(w_off, w_dcn, wo_a, wd_a);
  k_x2<<<4356, 256, 0, stream>>>(x, x2);
  k_offconv<<<512, 256, 0, stream>>>(x2, wo_a, b_off, wpart);
  k_dcn<<<2048, 256, 0, stream>>>(x2, wpart, wd_a, b_dcn, dcnb);
  k_ln<<<512, 256, 0, stream>>>(dcnb, x, gamma, beta, out);
}